// Round 6
// baseline (200.984 us; speedup 1.0000x reference)
//
#include <hip/hip_runtime.h>
#include <hip/hip_bf16.h>
#include <stdint.h>

#define B_ 4
#define S_ 1024
#define D_ 1024
#define E_ 8
#define DE_ 128
#define SCALE_ 0.03125f   // 1/sqrt(1024)

typedef __attribute__((ext_vector_type(8))) short short8;
typedef __attribute__((ext_vector_type(4))) float f32x4;
typedef unsigned short ushort_t;
typedef unsigned int uint32;

__device__ __forceinline__ ushort_t f2bf(float f) {
    uint32 u = __float_as_uint(f);
    uint32 r = u + 0x7fffu + ((u >> 16) & 1u);   // round-to-nearest-even
    return (ushort_t)(r >> 16);
}

// ---------------------------------------------------------------------------
// Kernel 1 (fused prep): K fp32 -> bf16 Kb [B][E][S][DE]
//                        V fp32 -> bf16 transposed Vt [B][E][DE][S]
// Grid (16 s-chunks of 64, 8 e, 4 b) = 512 blocks.
// ---------------------------------------------------------------------------
__global__ __launch_bounds__(256) void prep_kernel(
        const float* __restrict__ K, const float* __restrict__ V,
        ushort_t* __restrict__ Kb, ushort_t* __restrict__ Vt) {
    __shared__ ushort_t tile[64][130];   // pitch 130: 2-way-free on col walk
    const int tid = threadIdx.x;
    const int sc = blockIdx.x, e = blockIdx.y, b = blockIdx.z;
    const int s0 = sc * 64;
    const size_t plane = ((size_t)(b * 8 + e)) << 17;

    // K convert (64 x 128) + V stage to LDS
    #pragma unroll
    for (int i = 0; i < 8; ++i) {
        int idx = tid + i * 256, r = idx >> 5, c4 = idx & 31;
        size_t in_off = ((size_t)(b * 1024 + s0 + r) << 10) + (e << 7) + (c4 << 2);
        float4 k = *(const float4*)(K + in_off);
        float4 v = *(const float4*)(V + in_off);
        *(ushort4*)(Kb + plane + (((size_t)(s0 + r)) << 7) + (c4 << 2)) =
            make_ushort4(f2bf(k.x), f2bf(k.y), f2bf(k.z), f2bf(k.w));
        ushort_t* p = &tile[r][c4 << 2];
        p[0] = f2bf(v.x); p[1] = f2bf(v.y); p[2] = f2bf(v.z); p[3] = f2bf(v.w);
    }
    __syncthreads();
    // V transpose out: 128 d x 8 s-groups
    #pragma unroll
    for (int i = 0; i < 4; ++i) {
        int item = tid + i * 256, d = item & 127, sg = item >> 7;
        union { uint4 q; ushort_t u[8]; } tmp;
        #pragma unroll
        for (int j = 0; j < 8; ++j) tmp.u[j] = tile[sg * 8 + j][d];
        *(uint4*)(Vt + plane + (((size_t)d) << 10) + s0 + (sg << 3)) = tmp.q;
    }
}

// ---------------------------------------------------------------------------
// Kernel 2: lsums[b][e][s] = sum_t exp(scale * (Q_e K_e^T)[s][t])
// Grid (stile32=32, e=8, b=4); absent experts exit. 4 waves; wave w owns
// t in [256w, 256w+256). NO prob stores. Loads batched 16x behind
// sched_barrier so the scheduler cannot re-serialize them.
// ---------------------------------------------------------------------------
__global__ __launch_bounds__(256, 2) void attn_pass1(
        const float* __restrict__ Q, const ushort_t* __restrict__ Kb,
        const int* __restrict__ em, float* __restrict__ lsums) {

    __shared__ float redbuf[4][32];

    const int stile = blockIdx.x, e = blockIdx.y, b = blockIdx.z;
    if (em[e * B_ + b] == 0) return;                 // uniform

    const int tid  = threadIdx.x;
    const int w    = tid >> 6, lane = tid & 63;
    const int quad = lane >> 4, l16 = lane & 15;
    const int s0 = stile * 32;

    // A-frags: 2 s16-tiles x 4 k-frags, Q fp32 -> bf16 in-reg
    short8 af[2][4];
    #pragma unroll
    for (int sr = 0; sr < 2; ++sr) {
        const float* qb = Q + ((size_t)(b * 1024 + s0 + sr * 16 + l16) << 10)
                            + (e << 7) + quad * 8;
        #pragma unroll
        for (int kk = 0; kk < 4; ++kk) {
            float4 q0 = *(const float4*)(qb + kk * 32);
            float4 q1 = *(const float4*)(qb + kk * 32 + 4);
            union { short8 v; ushort_t u[8]; } a;
            a.u[0] = f2bf(q0.x); a.u[1] = f2bf(q0.y); a.u[2] = f2bf(q0.z); a.u[3] = f2bf(q0.w);
            a.u[4] = f2bf(q1.x); a.u[5] = f2bf(q1.y); a.u[6] = f2bf(q1.z); a.u[7] = f2bf(q1.w);
            af[sr][kk] = a.v;
        }
    }

    const ushort_t* kbase = Kb + (((size_t)(b * 8 + e)) << 17)
                               + (((size_t)(w * 256 + l16)) << 7) + quad * 8;
    float rsum[2][4] = {{0.f,0.f,0.f,0.f},{0.f,0.f,0.f,0.f}};

    for (int tb = 0; tb < 4; ++tb) {
        short8 kfr[16];
        #pragma unroll
        for (int j = 0; j < 4; ++j)
            #pragma unroll
            for (int kk = 0; kk < 4; ++kk)
                kfr[j * 4 + kk] = *(const short8*)(
                    kbase + (((size_t)(tb * 4 + j)) << 11) + (kk << 5));
        __builtin_amdgcn_sched_barrier(0);   // keep all 16 loads in flight

        f32x4 sacc[2][4];
        #pragma unroll
        for (int sr = 0; sr < 2; ++sr)
            #pragma unroll
            for (int j = 0; j < 4; ++j) sacc[sr][j] = (f32x4){0.f,0.f,0.f,0.f};
        #pragma unroll
        for (int j = 0; j < 4; ++j)
            #pragma unroll
            for (int kk = 0; kk < 4; ++kk)
                #pragma unroll
                for (int sr = 0; sr < 2; ++sr)
                    sacc[sr][j] = __builtin_amdgcn_mfma_f32_16x16x32_bf16(
                        af[sr][kk], kfr[j * 4 + kk], sacc[sr][j], 0, 0, 0);
        #pragma unroll
        for (int sr = 0; sr < 2; ++sr)
            #pragma unroll
            for (int j = 0; j < 4; ++j)
                #pragma unroll
                for (int r = 0; r < 4; ++r)
                    rsum[sr][r] += __expf(sacc[sr][j][r] * SCALE_);
    }

    // reduce over l16 lanes (t-cols), stash per-wave partials
    #pragma unroll
    for (int off = 1; off < 16; off <<= 1)
        #pragma unroll
        for (int sr = 0; sr < 2; ++sr)
            #pragma unroll
            for (int r = 0; r < 4; ++r)
                rsum[sr][r] += __shfl_xor(rsum[sr][r], off, 64);
    if (l16 == 0) {
        #pragma unroll
        for (int sr = 0; sr < 2; ++sr)
            #pragma unroll
            for (int r = 0; r < 4; ++r)
                redbuf[w][sr * 16 + quad * 4 + r] = rsum[sr][r];
    }
    __syncthreads();
    if (tid < 32) {
        float l = redbuf[0][tid] + redbuf[1][tid] + redbuf[2][tid] + redbuf[3][tid];
        lsums[(((size_t)(b * 8 + e)) << 10) + s0 + tid] = l;
    }
}

// ---------------------------------------------------------------------------
// Kernel 3: attnB[b][s][t] = bf16( sum_e mask * exp(scale*QK)[s][t]/l_e[s] )
// Recomputes QK (MFMA is cheap) instead of storing/reloading 76 MB of probs.
// Grid (stile16=64, tquad=4, b=4) = 1024 blocks; wave w owns t-strip
// [tq*256 + 64w, +64).
// ---------------------------------------------------------------------------
__global__ __launch_bounds__(256, 2) void attn_passC(
        const float* __restrict__ Q, const ushort_t* __restrict__ Kb,
        const float* __restrict__ lsums, const int* __restrict__ em,
        ushort_t* __restrict__ attnB) {

    const int stile = blockIdx.x, tq = blockIdx.y, b = blockIdx.z;
    const int tid  = threadIdx.x;
    const int w    = tid >> 6, lane = tid & 63;
    const int quad = lane >> 4, l16 = lane & 15;
    const int s0 = stile * 16;
    const int t0 = tq * 256 + w * 64;

    f32x4 aacc[4];
    #pragma unroll
    for (int j = 0; j < 4; ++j) aacc[j] = (f32x4){0.f,0.f,0.f,0.f};

    for (int e = 0; e < 8; ++e) {
        if (em[e * B_ + b] == 0) continue;          // uniform

        short8 af[4];
        const float* qb = Q + ((size_t)(b * 1024 + s0 + l16) << 10) + (e << 7) + quad * 8;
        #pragma unroll
        for (int kk = 0; kk < 4; ++kk) {
            float4 q0 = *(const float4*)(qb + kk * 32);
            float4 q1 = *(const float4*)(qb + kk * 32 + 4);
            union { short8 v; ushort_t u[8]; } a;
            a.u[0] = f2bf(q0.x); a.u[1] = f2bf(q0.y); a.u[2] = f2bf(q0.z); a.u[3] = f2bf(q0.w);
            a.u[4] = f2bf(q1.x); a.u[5] = f2bf(q1.y); a.u[6] = f2bf(q1.z); a.u[7] = f2bf(q1.w);
            af[kk] = a.v;
        }
        const ushort_t* kbase = Kb + (((size_t)(b * 8 + e)) << 17)
                                   + (((size_t)(t0 + l16)) << 7) + quad * 8;
        short8 kfr[16];
        #pragma unroll
        for (int j = 0; j < 4; ++j)
            #pragma unroll
            for (int kk = 0; kk < 4; ++kk)
                kfr[j * 4 + kk] = *(const short8*)(
                    kbase + (((size_t)j) << 11) + (kk << 5));
        __builtin_amdgcn_sched_barrier(0);

        f32x4 sacc[4];
        #pragma unroll
        for (int j = 0; j < 4; ++j) sacc[j] = (f32x4){0.f,0.f,0.f,0.f};
        #pragma unroll
        for (int j = 0; j < 4; ++j)
            #pragma unroll
            for (int kk = 0; kk < 4; ++kk)
                sacc[j] = __builtin_amdgcn_mfma_f32_16x16x32_bf16(
                    af[kk], kfr[j * 4 + kk], sacc[j], 0, 0, 0);

        float4 lv = *(const float4*)(lsums + (((size_t)(b * 8 + e)) << 10) + s0 + quad * 4);
        float rinv[4] = {1.0f / lv.x, 1.0f / lv.y, 1.0f / lv.z, 1.0f / lv.w};
        #pragma unroll
        for (int j = 0; j < 4; ++j)
            #pragma unroll
            for (int r = 0; r < 4; ++r)
                aacc[j][r] += __expf(sacc[j][r] * SCALE_) * rinv[r];
    }

    ushort_t* abase = attnB + (((size_t)(b * 1024 + s0)) << 10);
    #pragma unroll
    for (int j = 0; j < 4; ++j)
        #pragma unroll
        for (int r = 0; r < 4; ++r)
            abase[(((size_t)(quad * 4 + r)) << 10) + t0 + j * 16 + l16] = f2bf(aacc[j][r]);
}

// ---------------------------------------------------------------------------
// Kernel 4: out[b][s][e*128+d] = attn @ V_e if e in top2 else 0.
// Grid (64, 8, 4); unselected blocks zero-fill (replaces memset).
// ---------------------------------------------------------------------------
__global__ __launch_bounds__(256, 2) void attn_pass2(
        const ushort_t* __restrict__ Vt, const ushort_t* __restrict__ attnB,
        const float* __restrict__ route, float* __restrict__ out) {

    const int stile = blockIdx.x, e = blockIdx.y, b = blockIdx.z;
    const int s0  = stile * 16;
    const int tid = threadIdx.x;
    const int w = tid >> 6, lane = tid & 63, quad = lane >> 4, l16 = lane & 15;

    // top-2 (uniform; ties -> lower index, matches lax.top_k)
    const float* rp = route + b * 8;
    float v1 = rp[0]; int i1 = 0;
    #pragma unroll
    for (int i = 1; i < 8; ++i) { float v = rp[i]; if (v > v1) { v1 = v; i1 = i; } }
    float v2 = -1e30f; int i2 = 0;
    #pragma unroll
    for (int i = 0; i < 8; ++i) {
        if (i == i1) continue;
        float v = rp[i]; if (v > v2) { v2 = v; i2 = i; }
    }
    float* obase = out + (((size_t)(b * 1024 + s0)) << 10) + e * 128;

    if (e != i1 && e != i2) {
        #pragma unroll
        for (int i = 0; i < 2; ++i) {
            int idx = tid + i * 256, r = idx >> 5, cc = (idx & 31) << 2;
            *(float4*)&obase[(((size_t)r) << 10) + cc] = make_float4(0.f, 0.f, 0.f, 0.f);
        }
        return;
    }

    const ushort_t* abase = attnB + (((size_t)(b * 1024 + s0 + l16)) << 10) + quad * 8;
    const ushort_t* vbase = Vt + (((size_t)(b * 8 + e)) << 17)
                               + (((size_t)(w * 32 + l16)) << 10) + quad * 8;

    f32x4 oacc[2];
    oacc[0] = (f32x4){0.f, 0.f, 0.f, 0.f};
    oacc[1] = (f32x4){0.f, 0.f, 0.f, 0.f};

    for (int tb = 0; tb < 4; ++tb) {
        short8 A[8], B0[8], B1[8];
        #pragma unroll
        for (int j = 0; j < 8; ++j) {
            int ts = tb * 8 + j;
            A[j]  = *(const short8*)(abase + (ts << 5));
            B0[j] = *(const short8*)(vbase + (ts << 5));
            B1[j] = *(const short8*)(vbase + (16 << 10) + (ts << 5));
        }
        __builtin_amdgcn_sched_barrier(0);
        #pragma unroll
        for (int j = 0; j < 8; ++j) {
            oacc[0] = __builtin_amdgcn_mfma_f32_16x16x32_bf16(A[j], B0[j], oacc[0], 0, 0, 0);
            oacc[1] = __builtin_amdgcn_mfma_f32_16x16x32_bf16(A[j], B1[j], oacc[1], 0, 0, 0);
        }
    }

    #pragma unroll
    for (int n = 0; n < 2; ++n)
        #pragma unroll
        for (int r = 0; r < 4; ++r)
            obase[(((size_t)(quad * 4 + r)) << 10) + w * 32 + n * 16 + l16] = oacc[n][r];
}

// ---------------------------------------------------------------------------
extern "C" void kernel_launch(void* const* d_in, const int* in_sizes, int n_in,
                              void* d_out, int out_size, void* d_ws, size_t ws_size,
                              hipStream_t stream) {
    const float* Q     = (const float*)d_in[0];
    const float* K     = (const float*)d_in[1];
    const float* V     = (const float*)d_in[2];
    const float* route = (const float*)d_in[3];
    const int*   em    = (const int*)d_in[4];
    float* out = (float*)d_out;

    const size_t NB = (size_t)B_ * E_ * S_ * DE_;     // 4.19M elems
    ushort_t* Kb = (ushort_t*)d_ws;
    ushort_t* Vt = Kb + NB;
    float*    lsums = (float*)(Vt + NB);              // [B][E][S]
    ushort_t* attnB = (ushort_t*)(lsums + (size_t)B_ * E_ * S_);  // [B][S][S] bf16

    dim3 gp(16, 8, 4);
    prep_kernel<<<gp, 256, 0, stream>>>(K, V, Kb, Vt);
    dim3 g1(32, 8, 4);
    attn_pass1<<<g1, 256, 0, stream>>>(Q, Kb, em, lsums);
    dim3 gc(64, 4, 4);
    attn_passC<<<gc, 256, 0, stream>>>(Q, Kb, lsums, em, attnB);
    dim3 g2(64, 8, 4);
    attn_pass2<<<g2, 256, 0, stream>>>(Vt, attnB, route, out);
}

// Round 7
// 139.278 us; speedup vs baseline: 1.4430x; 1.4430x over previous
//
#include <hip/hip_runtime.h>
#include <hip/hip_bf16.h>
#include <stdint.h>

#define B_ 4
#define S_ 1024
#define D_ 1024
#define E_ 8
#define DE_ 128
#define SCALE_ 0.03125f   // 1/sqrt(1024)

typedef __attribute__((ext_vector_type(8))) short short8;
typedef __attribute__((ext_vector_type(4))) float f32x4;
typedef unsigned short ushort_t;
typedef unsigned int uint32;

__device__ __forceinline__ ushort_t f2bf(float f) {
    uint32 u = __float_as_uint(f);
    uint32 r = u + 0x7fffu + ((u >> 16) & 1u);   // round-to-nearest-even
    return (ushort_t)(r >> 16);
}

// Async global->LDS DMA, 16B/lane. LDS dst is wave-uniform base + lane*16.
#define GLOAD_LDS16(g, l) __builtin_amdgcn_global_load_lds( \
    (const __attribute__((address_space(1))) unsigned int*)(g), \
    (__attribute__((address_space(3))) unsigned int*)(l), 16, 0, 0)

// Stage a 64-row x 128-bf16 tile (16 KB) with XOR-swizzled chunk order.
// Global row stride = `stride` ushorts. LDS layout: row r, 16B-chunk slot
// (c ^ (r&7)) holds logical chunk c.
__device__ __forceinline__ void stage64(const ushort_t* __restrict__ g,
                                        size_t stride, ushort_t* lds,
                                        int w, int lane) {
    #pragma unroll
    for (int j = 0; j < 4; ++j) {
        int cb = (w * 4 + j) << 6;
        int ch = cb + lane;
        int r = ch >> 4, c = ch & 15;
        GLOAD_LDS16(g + (size_t)r * stride + ((c ^ (r & 7)) << 3),
                    lds + ((size_t)cb << 3));
    }
}
// Same for 128-row tile (32 KB).
__device__ __forceinline__ void stage128(const ushort_t* __restrict__ g,
                                         size_t stride, ushort_t* lds,
                                         int w, int lane) {
    #pragma unroll
    for (int j = 0; j < 8; ++j) {
        int cb = (w * 8 + j) << 6;
        int ch = cb + lane;
        int r = ch >> 4, c = ch & 15;
        GLOAD_LDS16(g + (size_t)r * stride + ((c ^ (r & 7)) << 3),
                    lds + ((size_t)cb << 3));
    }
}
// Read one MFMA frag (16B) from a swizzled tile. c = logical chunk 0..15.
__device__ __forceinline__ short8 fld(const ushort_t* lds, int row, int c) {
    return *(const short8*)(lds + (((row << 4) + (c ^ (row & 7))) << 3));
}

__device__ __forceinline__ void top2(const float* rp, int& i1, int& i2) {
    float v1 = rp[0]; i1 = 0;
    #pragma unroll
    for (int i = 1; i < 8; ++i) { float v = rp[i]; if (v > v1) { v1 = v; i1 = i; } }
    float v2 = -1e30f; i2 = 0;
    #pragma unroll
    for (int i = 0; i < 8; ++i) {
        if (i == i1) continue;
        float v = rp[i]; if (v > v2) { v2 = v; i2 = i; }
    }
}

// ---------------------------------------------------------------------------
// Kernel 1: prep. Q,K fp32 -> bf16 [B][E][S][DE] (only em-active planes);
// V fp32 -> bf16 transposed Vt [B][E][DE][S] (only top-2 selected planes).
// Grid (16 sc, 8 e, 4 b).
// ---------------------------------------------------------------------------
__global__ __launch_bounds__(256) void prep_kernel(
        const float* __restrict__ Q, const float* __restrict__ K,
        const float* __restrict__ V, const float* __restrict__ route,
        const int* __restrict__ em,
        ushort_t* __restrict__ Qb, ushort_t* __restrict__ Kb,
        ushort_t* __restrict__ Vt) {
    __shared__ ushort_t tile[64][130];
    const int tid = threadIdx.x;
    const int sc = blockIdx.x, e = blockIdx.y, b = blockIdx.z;
    const int s0 = sc * 64;
    const size_t plane = ((size_t)(b * 8 + e)) << 17;

    const bool ak = em[e * B_ + b] != 0;
    int i1, i2; top2(route + b * 8, i1, i2);
    const bool av = (e == i1) || (e == i2);
    if (!ak && !av) return;

    if (ak) {
        #pragma unroll
        for (int i = 0; i < 8; ++i) {
            int idx = tid + i * 256, r = idx >> 5, c4 = idx & 31;
            size_t in_off = ((size_t)(b * 1024 + s0 + r) << 10) + (e << 7) + (c4 << 2);
            float4 q = *(const float4*)(Q + in_off);
            float4 k = *(const float4*)(K + in_off);
            size_t oo = plane + (((size_t)(s0 + r)) << 7) + (c4 << 2);
            *(ushort4*)(Qb + oo) = make_ushort4(f2bf(q.x), f2bf(q.y), f2bf(q.z), f2bf(q.w));
            *(ushort4*)(Kb + oo) = make_ushort4(f2bf(k.x), f2bf(k.y), f2bf(k.z), f2bf(k.w));
        }
    }
    if (av) {
        #pragma unroll
        for (int i = 0; i < 8; ++i) {
            int idx = tid + i * 256, r = idx >> 5, c4 = idx & 31;
            size_t in_off = ((size_t)(b * 1024 + s0 + r) << 10) + (e << 7) + (c4 << 2);
            float4 v = *(const float4*)(V + in_off);
            ushort_t* p = &tile[r][c4 << 2];
            p[0] = f2bf(v.x); p[1] = f2bf(v.y); p[2] = f2bf(v.z); p[3] = f2bf(v.w);
        }
        __syncthreads();
        #pragma unroll
        for (int i = 0; i < 4; ++i) {
            int item = tid + i * 256, d = item & 127, sg = item >> 7;
            union { uint4 q; ushort_t u[8]; } tmp;
            #pragma unroll
            for (int j = 0; j < 8; ++j) tmp.u[j] = tile[sg * 8 + j][d];
            *(uint4*)(Vt + plane + (((size_t)d) << 10) + s0 + (sg << 3)) = tmp.q;
        }
    }
}

// ---------------------------------------------------------------------------
// Kernel 2: lsums[b][e][s] = sum_t exp(scale*(Q_e K_e^T)[s][t]).
// Grid (16 stile64, 8 e, 4 b), exit if !em. 4 waves in 2x2; LDS-staged
// 64x128 Q tile (once) + 128x128 K tile per t-chunk via global_load_lds.
// ---------------------------------------------------------------------------
__global__ __launch_bounds__(256, 2) void attn_pass1(
        const ushort_t* __restrict__ Qb, const ushort_t* __restrict__ Kb,
        const int* __restrict__ em, float* __restrict__ lsums) {

    __shared__ __align__(16) ushort_t qtile[64 * 128];
    __shared__ __align__(16) ushort_t ktile[128 * 128];
    __shared__ float red[2][64];

    const int stile = blockIdx.x, e = blockIdx.y, b = blockIdx.z;
    if (em[e * B_ + b] == 0) return;

    const int tid = threadIdx.x;
    const int w = tid >> 6, lane = tid & 63;
    const int quad = lane >> 4, l16 = lane & 15;
    const int wm = w & 1, wn = w >> 1;
    const int s0 = stile * 64;
    const size_t plane = ((size_t)(b * 8 + e)) << 17;

    stage64(Qb + plane + ((size_t)s0 << 7), 128, qtile, w, lane);
    stage128(Kb + plane, 128, ktile, w, lane);
    __syncthreads();

    short8 af[2][4];
    #pragma unroll
    for (int mi = 0; mi < 2; ++mi)
        #pragma unroll
        for (int kk = 0; kk < 4; ++kk)
            af[mi][kk] = fld(qtile, 32 * wm + 16 * mi + l16, (kk << 2) + quad);

    float rsum[2][4] = {{0.f,0.f,0.f,0.f},{0.f,0.f,0.f,0.f}};

    for (int tc = 0; tc < 8; ++tc) {
        f32x4 sacc[2][4];
        #pragma unroll
        for (int mi = 0; mi < 2; ++mi)
            #pragma unroll
            for (int ni = 0; ni < 4; ++ni) sacc[mi][ni] = (f32x4){0.f,0.f,0.f,0.f};
        #pragma unroll
        for (int ni = 0; ni < 4; ++ni)
            #pragma unroll
            for (int kk = 0; kk < 4; ++kk) {
                short8 bf = fld(ktile, 64 * wn + 16 * ni + l16, (kk << 2) + quad);
                #pragma unroll
                for (int mi = 0; mi < 2; ++mi)
                    sacc[mi][ni] = __builtin_amdgcn_mfma_f32_16x16x32_bf16(
                        af[mi][kk], bf, sacc[mi][ni], 0, 0, 0);
            }
        #pragma unroll
        for (int mi = 0; mi < 2; ++mi)
            #pragma unroll
            for (int ni = 0; ni < 4; ++ni)
                #pragma unroll
                for (int r = 0; r < 4; ++r)
                    rsum[mi][r] += __expf(sacc[mi][ni][r] * SCALE_);
        __syncthreads();
        if (tc < 7)
            stage128(Kb + plane + (((size_t)(tc + 1)) << 14), 128, ktile, w, lane);
        __syncthreads();
    }

    #pragma unroll
    for (int off = 1; off < 16; off <<= 1)
        #pragma unroll
        for (int mi = 0; mi < 2; ++mi)
            #pragma unroll
            for (int r = 0; r < 4; ++r)
                rsum[mi][r] += __shfl_xor(rsum[mi][r], off, 64);
    if (l16 == 0) {
        #pragma unroll
        for (int mi = 0; mi < 2; ++mi)
            #pragma unroll
            for (int r = 0; r < 4; ++r)
                red[wn][32 * wm + 16 * mi + quad * 4 + r] = rsum[mi][r];
    }
    __syncthreads();
    if (tid < 64)
        lsums[(((size_t)(b * 8 + e)) << 10) + s0 + tid] = red[0][tid] + red[1][tid];
}

// ---------------------------------------------------------------------------
// Kernel 3: attnB[b][s][t] = bf16( sum_e mask * exp(scale*QK)[s][t]/l_e[s] ).
// Grid (16 stile64, 8 ttile128, 4 b) = 512 blocks; loops active experts,
// staging Q/K tiles per expert; accumulates normalized probs in registers.
// ---------------------------------------------------------------------------
__global__ __launch_bounds__(256, 2) void attn_passC(
        const ushort_t* __restrict__ Qb, const ushort_t* __restrict__ Kb,
        const float* __restrict__ lsums, const int* __restrict__ em,
        ushort_t* __restrict__ attnB) {

    __shared__ __align__(16) ushort_t qtile[64 * 128];
    __shared__ __align__(16) ushort_t ktile[128 * 128];

    const int stile = blockIdx.x, tt = blockIdx.y, b = blockIdx.z;
    const int tid = threadIdx.x;
    const int w = tid >> 6, lane = tid & 63;
    const int quad = lane >> 4, l16 = lane & 15;
    const int wm = w & 1, wn = w >> 1;
    const int s0 = stile * 64, t0 = tt * 128;

    f32x4 aacc[2][4];
    #pragma unroll
    for (int mi = 0; mi < 2; ++mi)
        #pragma unroll
        for (int ni = 0; ni < 4; ++ni) aacc[mi][ni] = (f32x4){0.f,0.f,0.f,0.f};

    for (int e = 0; e < 8; ++e) {
        if (em[e * B_ + b] == 0) continue;
        const size_t plane = ((size_t)(b * 8 + e)) << 17;

        stage64(Qb + plane + ((size_t)s0 << 7), 128, qtile, w, lane);
        stage128(Kb + plane + ((size_t)t0 << 7), 128, ktile, w, lane);
        __syncthreads();

        float rinv[2][4];
        #pragma unroll
        for (int mi = 0; mi < 2; ++mi)
            #pragma unroll
            for (int r = 0; r < 4; ++r)
                rinv[mi][r] = 1.0f / lsums[(((size_t)(b * 8 + e)) << 10)
                                           + s0 + 32 * wm + 16 * mi + quad * 4 + r];

        short8 af[2][4];
        #pragma unroll
        for (int mi = 0; mi < 2; ++mi)
            #pragma unroll
            for (int kk = 0; kk < 4; ++kk)
                af[mi][kk] = fld(qtile, 32 * wm + 16 * mi + l16, (kk << 2) + quad);

        f32x4 sacc[2][4];
        #pragma unroll
        for (int mi = 0; mi < 2; ++mi)
            #pragma unroll
            for (int ni = 0; ni < 4; ++ni) sacc[mi][ni] = (f32x4){0.f,0.f,0.f,0.f};
        #pragma unroll
        for (int ni = 0; ni < 4; ++ni)
            #pragma unroll
            for (int kk = 0; kk < 4; ++kk) {
                short8 bf = fld(ktile, 64 * wn + 16 * ni + l16, (kk << 2) + quad);
                #pragma unroll
                for (int mi = 0; mi < 2; ++mi)
                    sacc[mi][ni] = __builtin_amdgcn_mfma_f32_16x16x32_bf16(
                        af[mi][kk], bf, sacc[mi][ni], 0, 0, 0);
            }
        #pragma unroll
        for (int mi = 0; mi < 2; ++mi)
            #pragma unroll
            for (int ni = 0; ni < 4; ++ni)
                #pragma unroll
                for (int r = 0; r < 4; ++r)
                    aacc[mi][ni][r] += __expf(sacc[mi][ni][r] * SCALE_) * rinv[mi][r];
        __syncthreads();
    }

    #pragma unroll
    for (int mi = 0; mi < 2; ++mi)
        #pragma unroll
        for (int ni = 0; ni < 4; ++ni)
            #pragma unroll
            for (int r = 0; r < 4; ++r)
                attnB[(((size_t)(b * 1024 + s0 + 32 * wm + 16 * mi + quad * 4 + r)) << 10)
                      + t0 + 64 * wn + 16 * ni + l16] = f2bf(aacc[mi][ni][r]);
}

// ---------------------------------------------------------------------------
// Kernel 4: out[b][s][e*128+d] = attn @ V_e if e in top2 else 0.
// Grid (16 stile64, 8 e, 4 b). Selected blocks: 8 t-chunks, staging
// 64x128 attn tile + 128x128 Vt tile per chunk.
// ---------------------------------------------------------------------------
__global__ __launch_bounds__(256, 2) void attn_pass2(
        const ushort_t* __restrict__ Vt, const ushort_t* __restrict__ attnB,
        const float* __restrict__ route, float* __restrict__ out) {

    __shared__ __align__(16) ushort_t atile[64 * 128];
    __shared__ __align__(16) ushort_t vtile[128 * 128];

    const int stile = blockIdx.x, e = blockIdx.y, b = blockIdx.z;
    const int tid = threadIdx.x;
    const int w = tid >> 6, lane = tid & 63;
    const int quad = lane >> 4, l16 = lane & 15;
    const int wm = w & 1, wn = w >> 1;
    const int s0 = stile * 64;

    int i1, i2; top2(route + b * 8, i1, i2);

    if (e != i1 && e != i2) {
        #pragma unroll
        for (int i = 0; i < 8; ++i) {
            int idx = tid + i * 256, r = idx >> 5, c4 = idx & 31;
            *(float4*)(out + (((size_t)(b * 1024 + s0 + r)) << 10) + (e << 7) + (c4 << 2))
                = make_float4(0.f, 0.f, 0.f, 0.f);
        }
        return;
    }

    const size_t vplane = ((size_t)(b * 8 + e)) << 17;
    const ushort_t* abase = attnB + (((size_t)(b * 1024 + s0)) << 10);

    f32x4 oacc[2][4];
    #pragma unroll
    for (int mi = 0; mi < 2; ++mi)
        #pragma unroll
        for (int ni = 0; ni < 4; ++ni) oacc[mi][ni] = (f32x4){0.f,0.f,0.f,0.f};

    for (int tc = 0; tc < 8; ++tc) {
        stage64(abase + (tc << 7), 1024, atile, w, lane);
        stage128(Vt + vplane + (tc << 7), 1024, vtile, w, lane);
        __syncthreads();

        short8 af[2][4];
        #pragma unroll
        for (int mi = 0; mi < 2; ++mi)
            #pragma unroll
            for (int kk = 0; kk < 4; ++kk)
                af[mi][kk] = fld(atile, 32 * wm + 16 * mi + l16, (kk << 2) + quad);
        #pragma unroll
        for (int ni = 0; ni < 4; ++ni)
            #pragma unroll
            for (int kk = 0; kk < 4; ++kk) {
                short8 bf = fld(vtile, 64 * wn + 16 * ni + l16, (kk << 2) + quad);
                #pragma unroll
                for (int mi = 0; mi < 2; ++mi)
                    oacc[mi][ni] = __builtin_amdgcn_mfma_f32_16x16x32_bf16(
                        af[mi][kk], bf, oacc[mi][ni], 0, 0, 0);
            }
        __syncthreads();
    }

    #pragma unroll
    for (int mi = 0; mi < 2; ++mi)
        #pragma unroll
        for (int ni = 0; ni < 4; ++ni)
            #pragma unroll
            for (int r = 0; r < 4; ++r)
                out[(((size_t)(b * 1024 + s0 + 32 * wm + 16 * mi + quad * 4 + r)) << 10)
                    + (e << 7) + 64 * wn + 16 * ni + l16] = oacc[mi][ni][r];
}

// ---------------------------------------------------------------------------
extern "C" void kernel_launch(void* const* d_in, const int* in_sizes, int n_in,
                              void* d_out, int out_size, void* d_ws, size_t ws_size,
                              hipStream_t stream) {
    const float* Q     = (const float*)d_in[0];
    const float* K     = (const float*)d_in[1];
    const float* V     = (const float*)d_in[2];
    const float* route = (const float*)d_in[3];
    const int*   em    = (const int*)d_in[4];
    float* out = (float*)d_out;

    const size_t NB = (size_t)B_ * E_ * S_ * DE_;     // 4.19M elems
    ushort_t* Qb = (ushort_t*)d_ws;
    ushort_t* Kb = Qb + NB;
    ushort_t* Vt = Kb + NB;
    float*    lsums = (float*)(Vt + NB);              // [B][E][S]
    ushort_t* attnB = (ushort_t*)(lsums + (size_t)B_ * E_ * S_);  // [B][S][S] bf16

    dim3 gp(16, 8, 4);
    prep_kernel<<<gp, 256, 0, stream>>>(Q, K, V, route, em, Qb, Kb, Vt);
    dim3 g1(16, 8, 4);
    attn_pass1<<<g1, 256, 0, stream>>>(Qb, Kb, em, lsums);
    dim3 gc(16, 8, 4);
    attn_passC<<<gc, 256, 0, stream>>>(Qb, Kb, lsums, em, attnB);
    dim3 g2(16, 8, 4);
    attn_pass2<<<g2, 256, 0, stream>>>(Vt, attnB, route, out);
}